// Round 12
// baseline (86.985 us; speedup 1.0000x reference)
//
#include <hip/hip_runtime.h>
#include <hip/hip_bf16.h>
#include <stdint.h>

// FullTucker: Z = U0 @ einsum('pqr,qb,rb->pb', G, U1^T@X1, U2^T@X2)
// D_OUT=D1=D2=512, R0=R1=R2=128, BATCH=8192. f32 in/out; bf16 MFMA inside.
// k_core: core[p,b] = sum_q x1[q,b] * (sum_r G[p,q,r]*u2[r,b])
//   R12 = R11 + residency fix: __launch_bounds__(256,4) so grid 1024 is
//   EXACTLY 4 resident blocks/CU (no 1-block tail batch) -> cross-block TLP
//   covers each block's barrier drain. x1 loads issued before stage-glds so
//   their vmcnt wait doesn't drain the staging queue.

typedef __attribute__((ext_vector_type(8))) short bf8;   // 8 bf16 (4 VGPR)
typedef __attribute__((ext_vector_type(4))) short bf4;   // 4 bf16 (8B)
typedef __attribute__((ext_vector_type(4))) float f4;    // 4 f32

__device__ __forceinline__ unsigned short f2bf(float f){
  unsigned x = __builtin_bit_cast(unsigned, f);
  x += 0x7fffu + ((x >> 16) & 1u);            // RNE (inputs finite)
  return (unsigned short)(x >> 16);
}
__device__ __forceinline__ float bf2f(unsigned short u){
  unsigned x = ((unsigned)u) << 16;
  return __builtin_bit_cast(float, x);
}
__device__ __forceinline__ void glds16(const void* g, void* l){
  __builtin_amdgcn_global_load_lds(
      (const __attribute__((address_space(1))) void*)g,
      (__attribute__((address_space(3))) void*)l, 16, 0, 0);
}

// ---------------- merged cast kernel ----------------
__global__ __launch_bounds__(256) void k_cast(const float* __restrict__ G,
                                              const float* __restrict__ U0,
                                              const float* __restrict__ U1,
                                              const float* __restrict__ U2,
                                              unsigned short* __restrict__ Gbf,
                                              unsigned short* __restrict__ U0bf,
                                              unsigned short* __restrict__ U1T,
                                              unsigned short* __restrict__ U2T){
  const int blk = blockIdx.x;
  if (blk < 2112){
    const int i4 = blk * 256 + threadIdx.x;                // 0..540671
    const int NG4 = 2097152 / 4;
    const float4* src; unsigned short* dst; int j4;
    if (i4 < NG4){ src = (const float4*)G;  dst = Gbf;  j4 = i4; }
    else         { src = (const float4*)U0; dst = U0bf; j4 = i4 - NG4; }
    float4 v = src[j4];
    ushort4 o = make_ushort4(f2bf(v.x), f2bf(v.y), f2bf(v.z), f2bf(v.w));
    ((ushort4*)dst)[j4] = o;
  } else {
    const int b2 = blk - 2112;                             // 0..511
    const float* U = (b2 < 256) ? U1 : U2;
    unsigned short* UT = (b2 < 256) ? U1T : U2T;
    const int idx = (b2 & 255) * 256 + threadIdx.x;        // 0..65535
    const int d = idx >> 7, q = idx & 127;
    UT[q * 512 + d] = f2bf(U[idx]);
  }
}

// ---------------- UX GEMM (both modes, one dispatch) ----------------
__global__ __launch_bounds__(256) void k_ux2(const unsigned short* __restrict__ U1T,
                                             const unsigned short* __restrict__ U2T,
                                             const float* __restrict__ X1,
                                             const float* __restrict__ X2,
                                             float* __restrict__ OUTF,
                                             unsigned short* __restrict__ OUTT){
  const bool second = (blockIdx.y != 0);
  const unsigned short* UT = second ? U2T : U1T;
  const float* X = second ? X2 : X1;
  __shared__ __align__(16) unsigned char lds[16384 + 8192];
  unsigned char* ldsA = lds;
  unsigned char* ldsB = lds + 16384;
  const int tid = threadIdx.x, lane = tid & 63, wv = tid >> 6;
  const int wr = wv >> 1, wc = wv & 1;
  const int b0 = blockIdx.x * 64;
  f4 acc[4][2] = {};

  for (int it = 0; it < 8; ++it){
    const int k0 = it * 64;
#pragma unroll
    for (int i = 0; i < 4; ++i){
      const int L = (wv * 4 + i) * 1024 + lane * 16;
      const int row = L >> 7;
      const int ss = (lane & 7) ^ (row & 7);
      glds16(UT + (size_t)row * 512 + k0 + ss * 8, ldsA + (wv * 4 + i) * 1024);
    }
#pragma unroll
    for (int c = 0; c < 2; ++c){
      const int slot = c * 4 + wv;
      const int bRow = lane;
      bf8 v;
#pragma unroll
      for (int j = 0; j < 8; ++j)
        v[j] = (short)f2bf(X[(size_t)(k0 + slot * 8 + j) * 8192 + b0 + bRow]);
      *(bf8*)(ldsB + bRow * 128 + ((slot ^ (bRow & 7)) << 4)) = v;
    }
    __syncthreads();
#pragma unroll
    for (int kc = 0; kc < 2; ++kc){
      const int g = lane >> 4;
      bf8 a[4], b[2];
#pragma unroll
      for (int mf = 0; mf < 4; ++mf){
        const int r = wr * 64 + mf * 16 + (lane & 15);
        a[mf] = *(const bf8*)(ldsA + r * 128 + (((kc * 4 + g) ^ (r & 7)) << 4));
      }
#pragma unroll
      for (int nf = 0; nf < 2; ++nf){
        const int rb = wc * 32 + nf * 16 + (lane & 15);
        b[nf] = *(const bf8*)(ldsB + rb * 128 + (((kc * 4 + g) ^ (rb & 7)) << 4));
      }
#pragma unroll
      for (int mf = 0; mf < 4; ++mf)
#pragma unroll
        for (int nf = 0; nf < 2; ++nf)
          acc[mf][nf] = __builtin_amdgcn_mfma_f32_16x16x32_bf16(a[mf], b[nf], acc[mf][nf], 0, 0, 0);
    }
    __syncthreads();
  }

  if (!second){
#pragma unroll
    for (int mf = 0; mf < 4; ++mf)
#pragma unroll
      for (int nf = 0; nf < 2; ++nf)
#pragma unroll
        for (int j = 0; j < 4; ++j){
          const int q = wr * 64 + mf * 16 + (lane >> 4) * 4 + j;
          const int b = b0 + wc * 32 + nf * 16 + (lane & 15);
          OUTF[(size_t)q * 8192 + b] = acc[mf][nf][j];
        }
  } else {
#pragma unroll
    for (int mf = 0; mf < 4; ++mf)
#pragma unroll
      for (int nf = 0; nf < 2; ++nf){
        const int rBase = wr * 64 + mf * 16 + (lane >> 4) * 4;
        const int bL = wc * 32 + nf * 16 + (lane & 15);
        bf4 p;
#pragma unroll
        for (int j = 0; j < 4; ++j) p[j] = (short)f2bf(acc[mf][nf][j]);
        *(bf4*)(lds + ((bL * 256 + rBase * 2) ^ ((bL & 7) << 4))) = p;
      }
    __syncthreads();
#pragma unroll
    for (int u = 0; u < 4; ++u){
      const int sIdx = u * 256 + tid;
      const int bL = sIdx >> 4, slot = sIdx & 15;
      bf8 v = *(const bf8*)(lds + bL * 256 + ((slot ^ (bL & 7)) << 4));
      *(bf8*)(OUTT + (size_t)(b0 + bL) * 128 + slot * 8) = v;
    }
  }
}

// ---------------- core: small-block TLP GEMM, 4 resident/CU, split-K(q)=8 ----------------
// Grid 1024 = EXACTLY 4 blocks/CU resident (launch_bounds min-waves/EU = 4).
// Block 64p x 128b, 4 waves (2 wr x 2 wc), wave 32p x 64b (mf=2, nf=4).
// LDS ring 2 x 16KB ([64p][128r] bf16, &15 swz) -> 4 x 32KB = 128KB/CU.
__global__ __launch_bounds__(256, 4) void k_core(const unsigned short* __restrict__ Gbf,  // [128][16384]
                                                 const float* __restrict__ UX1,           // [128][8192]
                                                 const unsigned short* __restrict__ UX2T, // [8192][128]
                                                 unsigned short* __restrict__ PT){        // [8][8192][128] bf16
  __shared__ __align__(16) unsigned char lds[32768];       // ring 2 x 16KB
  const int tid = threadIdx.x, lane = tid & 63;
  const int wv = tid >> 6;
  const int g = lane >> 4, l15 = lane & 15;
  const int wr = wv >> 1, wc = wv & 1;
  const int blk = blockIdx.x;                 // 0..1023; round-robin => xcd = blk&7
  const int split = blk & 7;                  // one split per XCD (G slice 512KB, L2-res)
  const int rest = blk >> 3;                  // 0..127
  const int pt = (rest & 1) * 64;             // p-tile 0 or 64
  const int b0 = (rest >> 1) * 128;           // 0..8064
  const int q0 = split * 16;

  // stage one 16KB q-slice [64p][128r] into ring buf (4 glds16 per thread).
  // LDS linear [row][slot*16]; source slot pre-swizzled ^ (row&15) so the
  // read-side XOR(l15) is conflict-free (R10/R11-measured: conflicts ~0).
  auto stageA = [&](int q, int buf){
#pragma unroll
    for (int rnd = 0; rnd < 4; ++rnd){
      const int off = rnd * 4096 + tid * 16;
      const int row = off >> 8;               // p-row 0..63
      const int slot = (off >> 4) & 15;
      const int ss = slot ^ (row & 15);       // source pre-swizzle
      glds16(Gbf + (size_t)(pt + row) * 16384 + (size_t)q * 128 + ss * 8,
             lds + buf * 16384 + off);
    }
  };

  // B hoist: Bf[kc][nf] = 16 bf8 = 64 VGPR, whole kernel
  bf8 Bf[4][4];
#pragma unroll
  for (int kc = 0; kc < 4; ++kc)
#pragma unroll
    for (int nf = 0; nf < 4; ++nf)
      Bf[kc][nf] = *(const bf8*)(UX2T + (size_t)(b0 + wc * 64 + nf * 16 + l15) * 128 +
                                 kc * 32 + g * 8);
  stageA(q0, 0);

  f4 acc[2][4];
#pragma unroll
  for (int mf = 0; mf < 2; ++mf)
#pragma unroll
    for (int nf = 0; nf < 4; ++nf) acc[mf][nf] = (f4){0.f, 0.f, 0.f, 0.f};

  for (int i = 0; i < 16; ++i){
    // syncthreads' vmcnt(0)+lgkm drain is REQUIRED by ring-2 (stage(i) landed;
    // body(i-1) reads retired before buf reuse). Three other resident blocks
    // keep the MFMA pipe fed while this one drains.
    __syncthreads();
    // x1 loads FIRST so their vmcnt wait doesn't drain the newer stage glds.
    float xs[4];
#pragma unroll
    for (int nf = 0; nf < 4; ++nf)
      xs[nf] = UX1[(size_t)(q0 + i) * 8192 + b0 + wc * 64 + nf * 16 + l15];
    if (i < 15) stageA(q0 + i + 1, (i + 1) & 1);

    // ---- body: pure C++, compiler-scheduled
    const unsigned char* A = lds + (i & 1) * 16384;
#pragma unroll
    for (int mf = 0; mf < 2; ++mf){
      const int row = wr * 32 + mf * 16 + l15;            // row&15 == l15
      bf8 a[4];
#pragma unroll
      for (int kc = 0; kc < 4; ++kc)
        a[kc] = *(const bf8*)(A + row * 256 + ((((kc << 2) + g) ^ l15) << 4));
#pragma unroll
      for (int nf = 0; nf < 4; ++nf){
        f4 y = __builtin_amdgcn_mfma_f32_16x16x32_bf16(a[0], Bf[0][nf], (f4){0.f,0.f,0.f,0.f}, 0, 0, 0);
        y = __builtin_amdgcn_mfma_f32_16x16x32_bf16(a[1], Bf[1][nf], y, 0, 0, 0);
        y = __builtin_amdgcn_mfma_f32_16x16x32_bf16(a[2], Bf[2][nf], y, 0, 0, 0);
        y = __builtin_amdgcn_mfma_f32_16x16x32_bf16(a[3], Bf[3][nf], y, 0, 0, 0);
        acc[mf][nf] += y * xs[nf];                        // fold x1 in f32
      }
    }
  }

  // epilogue: direct stores (C/D: col b = l15-part, rows g*4+j consecutive p)
#pragma unroll
  for (int mf = 0; mf < 2; ++mf)
#pragma unroll
    for (int nf = 0; nf < 4; ++nf){
      const int p = pt + wr * 32 + mf * 16 + g * 4;
      const int b = b0 + wc * 64 + nf * 16 + l15;
      ushort4 o = make_ushort4(f2bf(acc[mf][nf][0]), f2bf(acc[mf][nf][1]),
                               f2bf(acc[mf][nf][2]), f2bf(acc[mf][nf][3]));
      *(ushort4*)(PT + (size_t)split * 1048576 + (size_t)b * 128 + p) = o;
    }
}

// ---------------- reduce 8 split partials -> coreT bf16 [8192][128] ----------------
__global__ __launch_bounds__(256) void k_red(const unsigned short* __restrict__ PT,
                                             unsigned short* __restrict__ coreT){
  const int c = blockIdx.x * 256 + threadIdx.x;            // 0..131071 bf8 chunks
  const bf8* P = (const bf8*)PT;
  float s[8] = {};
#pragma unroll
  for (int sp = 0; sp < 8; ++sp){
    bf8 v = P[c + sp * 131072];
#pragma unroll
    for (int j = 0; j < 8; ++j) s[j] += bf2f((unsigned short)v[j]);
  }
  bf8 o;
#pragma unroll
  for (int j = 0; j < 8; ++j) o[j] = (short)f2bf(s[j]);
  ((bf8*)coreT)[c] = o;
}

// ---------------- Z = U0 @ core: M=512, N=8192, K=128 ----------------
__global__ __launch_bounds__(256) void k_z(const unsigned short* __restrict__ U0bf,  // [512][128]
                                           const unsigned short* __restrict__ coreT, // [8192][128]
                                           float* __restrict__ Z){                   // [512][8192]
  __shared__ __align__(16) unsigned char lds[32768];
  unsigned char* ldsA = lds;
  unsigned char* ldsB = lds + 16384;
  const int tid = threadIdx.x, lane = tid & 63, wv = tid >> 6;
  const int wr = wv >> 1, wc = wv & 1;
  const int b0 = blockIdx.x * 128;
  const int d0 = blockIdx.y * 128;
  f4 acc[4][4] = {};

#pragma unroll
  for (int it = 0; it < 2; ++it){
    const int k0 = it * 64;
#pragma unroll
    for (int i = 0; i < 4; ++i){
      const int L = (wv * 4 + i) * 1024 + lane * 16;
      const int row = L >> 7;
      const int ss = (lane & 7) ^ (row & 7);
      glds16(U0bf + (size_t)(d0 + row) * 128 + k0 + ss * 8, ldsA + (wv * 4 + i) * 1024);
      glds16(coreT + (size_t)(b0 + row) * 128 + k0 + ss * 8, ldsB + (wv * 4 + i) * 1024);
    }
    __syncthreads();
#pragma unroll
    for (int kc = 0; kc < 2; ++kc){
      const int g = lane >> 4;
      bf8 a[4], b[4];
#pragma unroll
      for (int mf = 0; mf < 4; ++mf){
        const int r = wr * 64 + mf * 16 + (lane & 15);
        a[mf] = *(const bf8*)(ldsA + r * 128 + (((kc * 4 + g) ^ (r & 7)) << 4));
      }
#pragma unroll
      for (int nf = 0; nf < 4; ++nf){
        const int rb = wc * 64 + nf * 16 + (lane & 15);
        b[nf] = *(const bf8*)(ldsB + rb * 128 + (((kc * 4 + g) ^ (rb & 7)) << 4));
      }
#pragma unroll
      for (int mf = 0; mf < 4; ++mf)
#pragma unroll
        for (int nf = 0; nf < 4; ++nf)
          acc[mf][nf] = __builtin_amdgcn_mfma_f32_16x16x32_bf16(a[mf], b[nf], acc[mf][nf], 0, 0, 0);
    }
    __syncthreads();
  }
#pragma unroll
  for (int mf = 0; mf < 4; ++mf)
#pragma unroll
    for (int nf = 0; nf < 4; ++nf)
#pragma unroll
      for (int j = 0; j < 4; ++j){
        const int d = d0 + wr * 64 + mf * 16 + (lane >> 4) * 4 + j;
        const int b = b0 + wc * 64 + nf * 16 + (lane & 15);
        Z[(size_t)d * 8192 + b] = acc[mf][nf][j];
      }
}

// ---------------- host launch ----------------
extern "C" void kernel_launch(void* const* d_in, const int* in_sizes, int n_in,
                              void* d_out, int out_size, void* d_ws, size_t ws_size,
                              hipStream_t stream){
  const float* X1 = (const float*)d_in[0];
  const float* X2 = (const float*)d_in[1];
  const float* U0 = (const float*)d_in[2];
  const float* U1 = (const float*)d_in[3];
  const float* U2 = (const float*)d_in[4];
  const float* G  = (const float*)d_in[5];
  float* Z = (float*)d_out;

  char* ws = (char*)d_ws;
  unsigned short* Gbf   = (unsigned short*)(ws);              //  4,194,304 B
  unsigned short* U0bf  = (unsigned short*)(ws + 4194304);    //    131,072 B
  unsigned short* U1T   = (unsigned short*)(ws + 4325376);    //    131,072 B
  unsigned short* U2T   = (unsigned short*)(ws + 4456448);    //    131,072 B
  float*          UX1   = (float*)         (ws + 4587520);    //  4,194,304 B
  unsigned short* UX2T  = (unsigned short*)(ws + 8781824);    //  2,097,152 B
  unsigned short* coreT = (unsigned short*)(ws + 10878976);   //  2,097,152 B
  unsigned short* PT    = (unsigned short*)(ws + 12976128);   // 16,777,216 B (bf16 x8 splits)

  k_cast<<<dim3(2624), dim3(256), 0, stream>>>(G, U0, U1, U2, Gbf, U0bf, U1T, U2T);
  k_ux2 <<<dim3(128, 2), dim3(256), 0, stream>>>(U1T, U2T, X1, X2, UX1, UX2T);
  k_core<<<dim3(1024), dim3(256), 0, stream>>>(Gbf, UX1, UX2T, PT);
  k_red <<<dim3(512), dim3(256), 0, stream>>>(PT, coreT);
  k_z   <<<dim3(64, 4), dim3(256), 0, stream>>>(U0bf, coreT, Z);
}

// Round 13
// 68.917 us; speedup vs baseline: 1.2622x; 1.2622x over previous
//
#include <hip/hip_runtime.h>
#include <hip/hip_bf16.h>
#include <stdint.h>

// FullTucker: Z = U0 @ einsum('pqr,qb,rb->pb', G, U1^T@X1, U2^T@X2)
// D_OUT=D1=D2=512, R0=R1=R2=128, BATCH=8192. f32 in/out; bf16 MFMA inside.
// R13 = R9 k_core (best measured: 43.4us, minimal-fence ring) + fused
// k_zred (split-reduce + U0 GEMM + Z store in one pass; kills coreT
// round-trip, k_red dispatch, and one launch).

typedef __attribute__((ext_vector_type(8))) short bf8;   // 8 bf16 (4 VGPR)
typedef __attribute__((ext_vector_type(4))) short bf4;   // 4 bf16 (8B)
typedef __attribute__((ext_vector_type(4))) float f4;    // 4 f32

__device__ __forceinline__ unsigned short f2bf(float f){
  unsigned x = __builtin_bit_cast(unsigned, f);
  x += 0x7fffu + ((x >> 16) & 1u);            // RNE (inputs finite)
  return (unsigned short)(x >> 16);
}
__device__ __forceinline__ float bf2f(unsigned short u){
  unsigned x = ((unsigned)u) << 16;
  return __builtin_bit_cast(float, x);
}
__device__ __forceinline__ void glds16(const void* g, void* l){
  __builtin_amdgcn_global_load_lds(
      (const __attribute__((address_space(1))) void*)g,
      (__attribute__((address_space(3))) void*)l, 16, 0, 0);
}

// ---------------- merged cast kernel ----------------
__global__ __launch_bounds__(256) void k_cast(const float* __restrict__ G,
                                              const float* __restrict__ U0,
                                              const float* __restrict__ U1,
                                              const float* __restrict__ U2,
                                              unsigned short* __restrict__ Gbf,
                                              unsigned short* __restrict__ U0bf,
                                              unsigned short* __restrict__ U1T,
                                              unsigned short* __restrict__ U2T){
  const int blk = blockIdx.x;
  if (blk < 2112){
    const int i4 = blk * 256 + threadIdx.x;                // 0..540671
    const int NG4 = 2097152 / 4;
    const float4* src; unsigned short* dst; int j4;
    if (i4 < NG4){ src = (const float4*)G;  dst = Gbf;  j4 = i4; }
    else         { src = (const float4*)U0; dst = U0bf; j4 = i4 - NG4; }
    float4 v = src[j4];
    ushort4 o = make_ushort4(f2bf(v.x), f2bf(v.y), f2bf(v.z), f2bf(v.w));
    ((ushort4*)dst)[j4] = o;
  } else {
    const int b2 = blk - 2112;                             // 0..511
    const float* U = (b2 < 256) ? U1 : U2;
    unsigned short* UT = (b2 < 256) ? U1T : U2T;
    const int idx = (b2 & 255) * 256 + threadIdx.x;        // 0..65535
    const int d = idx >> 7, q = idx & 127;
    UT[q * 512 + d] = f2bf(U[idx]);
  }
}

// ---------------- UX GEMM (both modes, one dispatch) ----------------
__global__ __launch_bounds__(256) void k_ux2(const unsigned short* __restrict__ U1T,
                                             const unsigned short* __restrict__ U2T,
                                             const float* __restrict__ X1,
                                             const float* __restrict__ X2,
                                             float* __restrict__ OUTF,
                                             unsigned short* __restrict__ OUTT){
  const bool second = (blockIdx.y != 0);
  const unsigned short* UT = second ? U2T : U1T;
  const float* X = second ? X2 : X1;
  __shared__ __align__(16) unsigned char lds[16384 + 8192];
  unsigned char* ldsA = lds;
  unsigned char* ldsB = lds + 16384;
  const int tid = threadIdx.x, lane = tid & 63, wv = tid >> 6;
  const int wr = wv >> 1, wc = wv & 1;
  const int b0 = blockIdx.x * 64;
  f4 acc[4][2] = {};

  for (int it = 0; it < 8; ++it){
    const int k0 = it * 64;
#pragma unroll
    for (int i = 0; i < 4; ++i){
      const int L = (wv * 4 + i) * 1024 + lane * 16;
      const int row = L >> 7;
      const int ss = (lane & 7) ^ (row & 7);
      glds16(UT + (size_t)row * 512 + k0 + ss * 8, ldsA + (wv * 4 + i) * 1024);
    }
#pragma unroll
    for (int c = 0; c < 2; ++c){
      const int slot = c * 4 + wv;
      const int bRow = lane;
      bf8 v;
#pragma unroll
      for (int j = 0; j < 8; ++j)
        v[j] = (short)f2bf(X[(size_t)(k0 + slot * 8 + j) * 8192 + b0 + bRow]);
      *(bf8*)(ldsB + bRow * 128 + ((slot ^ (bRow & 7)) << 4)) = v;
    }
    __syncthreads();
#pragma unroll
    for (int kc = 0; kc < 2; ++kc){
      const int g = lane >> 4;
      bf8 a[4], b[2];
#pragma unroll
      for (int mf = 0; mf < 4; ++mf){
        const int r = wr * 64 + mf * 16 + (lane & 15);
        a[mf] = *(const bf8*)(ldsA + r * 128 + (((kc * 4 + g) ^ (r & 7)) << 4));
      }
#pragma unroll
      for (int nf = 0; nf < 2; ++nf){
        const int rb = wc * 32 + nf * 16 + (lane & 15);
        b[nf] = *(const bf8*)(ldsB + rb * 128 + (((kc * 4 + g) ^ (rb & 7)) << 4));
      }
#pragma unroll
      for (int mf = 0; mf < 4; ++mf)
#pragma unroll
        for (int nf = 0; nf < 2; ++nf)
          acc[mf][nf] = __builtin_amdgcn_mfma_f32_16x16x32_bf16(a[mf], b[nf], acc[mf][nf], 0, 0, 0);
    }
    __syncthreads();
  }

  if (!second){
#pragma unroll
    for (int mf = 0; mf < 4; ++mf)
#pragma unroll
      for (int nf = 0; nf < 2; ++nf)
#pragma unroll
        for (int j = 0; j < 4; ++j){
          const int q = wr * 64 + mf * 16 + (lane >> 4) * 4 + j;
          const int b = b0 + wc * 32 + nf * 16 + (lane & 15);
          OUTF[(size_t)q * 8192 + b] = acc[mf][nf][j];
        }
  } else {
#pragma unroll
    for (int mf = 0; mf < 4; ++mf)
#pragma unroll
      for (int nf = 0; nf < 2; ++nf){
        const int rBase = wr * 64 + mf * 16 + (lane >> 4) * 4;
        const int bL = wc * 32 + nf * 16 + (lane & 15);
        bf4 p;
#pragma unroll
        for (int j = 0; j < 4; ++j) p[j] = (short)f2bf(acc[mf][nf][j]);
        *(bf4*)(lds + ((bL * 256 + rBase * 2) ^ ((bL & 7) << 4))) = p;
      }
    __syncthreads();
#pragma unroll
    for (int u = 0; u < 4; ++u){
      const int sIdx = u * 256 + tid;
      const int bL = sIdx >> 4, slot = sIdx & 15;
      bf8 v = *(const bf8*)(lds + bL * 256 + ((slot ^ (bL & 7)) << 4));
      *(bf8*)(OUTT + (size_t)(b0 + bL) * 128 + slot * 8) = v;
    }
  }
}

// ---------------- core: R9 minimal-fence ring GEMM, split-K(q)=8 ----------------
// Grid 256 (1 block/CU). Block 128p x 256b, 8 waves (2x4), wave 64p x 64b.
// LDS: A ring 3 x 32KB ([128p][128r] bf16, swizzled) + x1 [16q][256b] f32 16KB.
__global__ __launch_bounds__(512, 2) void k_core(const unsigned short* __restrict__ Gbf,  // [128][16384]
                                                 const float* __restrict__ UX1,           // [128][8192]
                                                 const unsigned short* __restrict__ UX2T, // [8192][128]
                                                 unsigned short* __restrict__ PT){        // [8][8192][128] bf16
  __shared__ __align__(16) unsigned char lds[114688];      // 3x32K ring + 16K x1
  unsigned char* ldsX = lds + 98304;
  const int tid = threadIdx.x, lane = tid & 63, wv = tid >> 6;
  const int g = lane >> 4, l15 = lane & 15;
  const int wr = wv >> 2, wc = wv & 3;          // 2 x 4 waves; wave 64p x 64b
  const int blk = blockIdx.x;                   // 0..255; round-robin => xcd = blk&7
  const int split = blk & 7;                    // one split per XCD (G slice 512KB, L2-res)
  const int b0 = (blk >> 3) * 256;              // 0..7936
  const int q0 = split * 16;

  // stage one 32KB q-slice [128p][128r] into ring buf (4 glds16 per wave)
  auto stageA = [&](int q, int buf){
#pragma unroll
    for (int rnd = 0; rnd < 4; ++rnd){
      const int off = rnd * 8192 + wv * 1024 + lane * 16;
      const int row = off >> 8;                 // p-row 0..127
      const int ss = ((off >> 4) & 15) ^ (row & 7);   // source pre-swizzle
      glds16(Gbf + (size_t)row * 16384 + (size_t)q * 128 + ss * 8,
             lds + buf * 32768 + off);
    }
  };

  // B hoist FIRST: 16 bf8 = 64 VGPR, whole kernel
  bf8 Bf[4][4];
#pragma unroll
  for (int kc = 0; kc < 4; ++kc)
#pragma unroll
    for (int nf = 0; nf < 4; ++nf)
      Bf[kc][nf] = *(const bf8*)(UX2T + (size_t)(b0 + wc * 64 + nf * 16 + l15) * 128 +
                                 kc * 32 + g * 8);
  // x1 slice [16q][256b] f32 -> LDS (2 glds)
#pragma unroll
  for (int rnd = 0; rnd < 2; ++rnd){
    const int off = rnd * 8192 + wv * 1024 + lane * 16;
    const int row = off >> 10;                  // q-row 0..15
    glds16(UX1 + (size_t)(q0 + row) * 8192 + b0 + ((off >> 2) & 255), ldsX + off);
  }
  stageA(q0 + 0, 0);
  stageA(q0 + 1, 1);

  f4 acc[4][4];
#pragma unroll
  for (int mf = 0; mf < 4; ++mf)
#pragma unroll
    for (int nf = 0; nf < 4; ++nf) acc[mf][nf] = (f4){0.f, 0.f, 0.f, 0.f};

  int cur = 0;                                  // ring buffer of body(i)
  for (int i = 0; i < 16; ++i){
    // ONE counted wait + ONE barrier per q; nothing else pins the schedule.
    if (i < 15) asm volatile("s_waitcnt vmcnt(4)" ::: "memory");
    else        asm volatile("s_waitcnt vmcnt(0)" ::: "memory");
    __builtin_amdgcn_s_barrier();
    if (i < 14){
      int sbuf = cur + 2; if (sbuf >= 3) sbuf -= 3;
      stageA(q0 + i + 2, sbuf);
    }

    // ---- body: pure C++, compiler-scheduled (fine lgkmcnt, MFMA interleave)
    const unsigned char* A = lds + cur * 32768;
    float xs[4];
#pragma unroll
    for (int nf = 0; nf < 4; ++nf)
      xs[nf] = *(const float*)(ldsX + i * 1024 + (wc * 64 + nf * 16 + l15) * 4);
#pragma unroll
    for (int mf = 0; mf < 4; ++mf){
      const int row = wr * 64 + mf * 16 + l15;
      bf8 a[4];
#pragma unroll
      for (int kc = 0; kc < 4; ++kc)
        a[kc] = *(const bf8*)(A + row * 256 + ((((kc << 2) + g) ^ (row & 7)) << 4));
#pragma unroll
      for (int nf = 0; nf < 4; ++nf){
        f4 y = __builtin_amdgcn_mfma_f32_16x16x32_bf16(a[0], Bf[0][nf], (f4){0.f,0.f,0.f,0.f}, 0, 0, 0);
        y = __builtin_amdgcn_mfma_f32_16x16x32_bf16(a[1], Bf[1][nf], y, 0, 0, 0);
        y = __builtin_amdgcn_mfma_f32_16x16x32_bf16(a[2], Bf[2][nf], y, 0, 0, 0);
        y = __builtin_amdgcn_mfma_f32_16x16x32_bf16(a[3], Bf[3][nf], y, 0, 0, 0);
        acc[mf][nf] += y * xs[nf];              // fold x1 in f32 (indep chain tail)
      }
    }
    ++cur; if (cur == 3) cur = 0;
  }

  // epilogue: acc -> PT[split][b][p] bf16 via swizzled LDS transpose (64KB in ring)
  __syncthreads();
#pragma unroll
  for (int mf = 0; mf < 4; ++mf)
#pragma unroll
    for (int nf = 0; nf < 4; ++nf){
      const int bL = wc * 64 + nf * 16 + l15;    // 0..255
      const int pq = wr * 16 + mf * 4 + g;       // p-quad 0..31
      bf4 o;
#pragma unroll
      for (int j = 0; j < 4; ++j) o[j] = (short)f2bf(acc[mf][nf][j]);
      *(bf4*)(lds + bL * 256 + ((pq ^ (bL & 7)) << 3)) = o;
    }
  __syncthreads();
#pragma unroll
  for (int rnd = 0; rnd < 8; ++rnd){
    const int idx = rnd * 512 + tid;             // 4096 x 16B chunks
    const int bL = idx >> 4, s8 = idx & 15;
    bf4 lo = *(const bf4*)(lds + bL * 256 + (((s8 * 2) ^ (bL & 7)) << 3));
    bf4 hi = *(const bf4*)(lds + bL * 256 + (((s8 * 2 + 1) ^ (bL & 7)) << 3));
    bf8 o;
#pragma unroll
    for (int j = 0; j < 4; ++j){ o[j] = lo[j]; o[4 + j] = hi[j]; }
    *(bf8*)(PT + (size_t)split * 1048576 + (size_t)(b0 + bL) * 128 + s8 * 8) = o;
  }
}

// ---------------- fused reduce + Z GEMM ----------------
// Grid 256 (1/CU), 512 thr. Block = 512 d x 32 b. Per block:
//  (1) cooperative reduce of 8 PT partials -> ldsB [32b][128k] bf16 (swizzled)
//  (2) A (U0bf) frags L2->reg (K=128 entire: 16 bf8/lane)
//  (3) one barrier, 32 MFMA/wave, direct f32 Z stores.
__global__ __launch_bounds__(512, 1) void k_zred(const unsigned short* __restrict__ U0bf, // [512][128]
                                                 const unsigned short* __restrict__ PT,   // [8][8192][128]
                                                 float* __restrict__ Z){                  // [512][8192]
  __shared__ __align__(16) unsigned char ldsB[8192];       // [32b][128k] bf16 swizzled
  const int tid = threadIdx.x, lane = tid & 63, wv = tid >> 6;
  const int g = lane >> 4, l15 = lane & 15;
  const int b0 = blockIdx.x * 32;

  // (1) reduce: thread t -> b = t>>4 (0..31), slot = t&15 (8 k-elems each)
  {
    const int b = tid >> 4, slot = tid & 15;
    float s[8] = {0.f, 0.f, 0.f, 0.f, 0.f, 0.f, 0.f, 0.f};
#pragma unroll
    for (int sp = 0; sp < 8; ++sp){
      bf8 v = *(const bf8*)(PT + ((size_t)sp * 8192 + b0 + b) * 128 + slot * 8);
#pragma unroll
      for (int j = 0; j < 8; ++j) s[j] += bf2f((unsigned short)v[j]);
    }
    bf8 o;
#pragma unroll
    for (int j = 0; j < 8; ++j) o[j] = (short)f2bf(s[j]);
    *(bf8*)(ldsB + b * 256 + ((slot ^ (b & 15)) << 4)) = o;
  }

  // (2) A frags: wave wv owns d-rows [wv*64, wv*64+64); 16 bf8 = 64 VGPR
  bf8 a[4][4];                                   // [mf][kc]
#pragma unroll
  for (int mf = 0; mf < 4; ++mf)
#pragma unroll
    for (int kc = 0; kc < 4; ++kc)
      a[mf][kc] = *(const bf8*)(U0bf + (size_t)(wv * 64 + mf * 16 + l15) * 128 +
                                kc * 32 + g * 8);

  __syncthreads();

  // (3) GEMM: K=128 (4 kc), wave tile 64d x 32b (mf=4, nf=2)
  f4 acc[4][2];
#pragma unroll
  for (int nf = 0; nf < 2; ++nf){
    bf8 bfr[4];
    const int row = nf * 16 + l15;
#pragma unroll
    for (int kc = 0; kc < 4; ++kc)
      bfr[kc] = *(const bf8*)(ldsB + row * 256 + ((((kc << 2) + g) ^ (row & 15)) << 4));
#pragma unroll
    for (int mf = 0; mf < 4; ++mf){
      f4 y = __builtin_amdgcn_mfma_f32_16x16x32_bf16(a[mf][0], bfr[0], (f4){0.f,0.f,0.f,0.f}, 0, 0, 0);
      y = __builtin_amdgcn_mfma_f32_16x16x32_bf16(a[mf][1], bfr[1], y, 0, 0, 0);
      y = __builtin_amdgcn_mfma_f32_16x16x32_bf16(a[mf][2], bfr[2], y, 0, 0, 0);
      y = __builtin_amdgcn_mfma_f32_16x16x32_bf16(a[mf][3], bfr[3], y, 0, 0, 0);
      acc[mf][nf] = y;
    }
  }

  // (4) store Z[d][b] f32 (C/D: b-col = l15, d-rows = g*4+j)
#pragma unroll
  for (int mf = 0; mf < 4; ++mf)
#pragma unroll
    for (int nf = 0; nf < 2; ++nf)
#pragma unroll
      for (int j = 0; j < 4; ++j){
        const int d = wv * 64 + mf * 16 + g * 4 + j;
        const int b = b0 + nf * 16 + l15;
        Z[(size_t)d * 8192 + b] = acc[mf][nf][j];
      }
}

// ---------------- host launch ----------------
extern "C" void kernel_launch(void* const* d_in, const int* in_sizes, int n_in,
                              void* d_out, int out_size, void* d_ws, size_t ws_size,
                              hipStream_t stream){
  const float* X1 = (const float*)d_in[0];
  const float* X2 = (const float*)d_in[1];
  const float* U0 = (const float*)d_in[2];
  const float* U1 = (const float*)d_in[3];
  const float* U2 = (const float*)d_in[4];
  const float* G  = (const float*)d_in[5];
  float* Z = (float*)d_out;

  char* ws = (char*)d_ws;
  unsigned short* Gbf   = (unsigned short*)(ws);              //  4,194,304 B
  unsigned short* U0bf  = (unsigned short*)(ws + 4194304);    //    131,072 B
  unsigned short* U1T   = (unsigned short*)(ws + 4325376);    //    131,072 B
  unsigned short* U2T   = (unsigned short*)(ws + 4456448);    //    131,072 B
  float*          UX1   = (float*)         (ws + 4587520);    //  4,194,304 B
  unsigned short* UX2T  = (unsigned short*)(ws + 8781824);    //  2,097,152 B
  unsigned short* PT    = (unsigned short*)(ws + 12976128);   // 16,777,216 B (bf16 x8 splits)

  k_cast<<<dim3(2624), dim3(256), 0, stream>>>(G, U0, U1, U2, Gbf, U0bf, U1T, U2T);
  k_ux2 <<<dim3(128, 2), dim3(256), 0, stream>>>(U1T, U2T, X1, X2, UX1, UX2T);
  k_core<<<dim3(256), dim3(512), 0, stream>>>(Gbf, UX1, UX2T, PT);
  k_zred<<<dim3(256), dim3(512), 0, stream>>>(U0bf, PT, Z);
}